// Round 7
// baseline (427.281 us; speedup 1.0000x reference)
//
#include <hip/hip_runtime.h>

#define N_NODES 50000
#define N_RELSR 20
#define R_TOT   41          // 2*N_RELSR + 1
#define N_EDGES 500000
#define EMB     16
#define NCLS    16
#define NB      40
#define E_TOT   (2 * N_EDGES + N_NODES)   // 1,050,000
#define NE_COL  (N_NODES * EMB)           // 800,000
#define NBLK_N  ((N_NODES + 255) / 256)   // 196

// f32 -> bf16 round-to-nearest-even (manual, no header dependency)
__device__ __forceinline__ unsigned short f2bf(float f) {
    unsigned u = __float_as_uint(f);
    u += 0x7FFFu + ((u >> 16) & 1u);
    return (unsigned short)(u >> 16);
}

// decode enriched edge i -> (s, o, r)
__device__ __forceinline__ void edge_decode(int i, const int* __restrict__ src,
                                            const int* __restrict__ dst,
                                            const int* __restrict__ rel,
                                            int& s, int& o, int& r) {
    if (i < N_EDGES) {
        s = src[i]; o = dst[i]; r = rel[i];
    } else if (i < 2 * N_EDGES) {
        int j = i - N_EDGES;
        s = dst[j]; o = src[j]; r = rel[j] + N_RELSR;
    } else {
        int n = i - 2 * N_EDGES;
        s = n; o = n; r = 2 * N_RELSR;
    }
}

// cnt2[idx] = { count, local r-prefix within node s }

// ---- K1: segment counts; also record each edge's rank within its segment ---
__global__ void k_count(const int* __restrict__ src, const int* __restrict__ dst,
                        const int* __restrict__ rel, int2* __restrict__ cnt2,
                        int* __restrict__ rank) {
    int i = blockIdx.x * blockDim.x + threadIdx.x;
    if (i >= E_TOT) return;
    int s, o, r;
    edge_decode(i, src, dst, rel, s, o, r);
    rank[i] = atomicAdd(&cnt2[r * N_NODES + s].x, 1);
}

// ---- K2a: deg[s] = sum_r cnt[r,s]; local r-prefix into .y; per-block sums ---
__global__ void k_degA(int2* __restrict__ cnt2, int* __restrict__ deg,
                       int* __restrict__ bsum) {
    __shared__ int red[256];
    int t = threadIdx.x;
    int s = blockIdx.x * 256 + t;
    int run = 0;
    if (s < N_NODES) {
        for (int r = 0; r < R_TOT; r++) {
            int idx = r * N_NODES + s;
            int2 val = cnt2[idx];
            val.y = run;              // local exclusive prefix over r
            cnt2[idx] = val;
            run += val.x;
        }
        deg[s] = run;
    }
    red[t] = run;
    __syncthreads();
    for (int st = 128; st > 0; st >>= 1) {
        if (t < st) red[t] += red[t + st];
        __syncthreads();
    }
    if (t == 0) bsum[blockIdx.x] = red[0];
}

// ---- K2b: exclusive scan of 196 block sums (single tiny block) --------------
__global__ void k_degB(int* __restrict__ bsum) {
    __shared__ int sh[256];
    int t = threadIdx.x;
    int v = (t < NBLK_N) ? bsum[t] : 0;
    sh[t] = v;
    __syncthreads();
    for (int d = 1; d < 256; d <<= 1) {
        int x = (t >= d) ? sh[t - d] : 0;
        __syncthreads();
        sh[t] += x;
        __syncthreads();
    }
    if (t < NBLK_N) bsum[t] = sh[t] - v;   // exclusive
}

// ---- K2c: block-local scan of deg -> off (global CSR offsets) ---------------
__global__ void k_degC(const int* __restrict__ deg, const int* __restrict__ bsum,
                       int* __restrict__ off) {
    __shared__ int sh[256];
    int t = threadIdx.x;
    int s = blockIdx.x * 256 + t;
    int d = (s < N_NODES) ? deg[s] : 0;
    sh[t] = d;
    __syncthreads();
    for (int dd = 1; dd < 256; dd <<= 1) {
        int x = (t >= dd) ? sh[t - dd] : 0;
        __syncthreads();
        sh[t] += x;
        __syncthreads();
    }
    int excl = sh[t] - d + bsum[blockIdx.x];
    if (s < N_NODES) off[s] = excl;
    if (s == 0) off[N_NODES] = E_TOT;
}

// ---- K3: fill CSR records {(r<<16)|o, v} sorted by (s, r); no atomics -------
__global__ void k_fill(const int* __restrict__ src, const int* __restrict__ dst,
                       const int* __restrict__ rel, const int2* __restrict__ cnt2,
                       const int* __restrict__ rank, const int* __restrict__ off,
                       int2* __restrict__ recs) {
    int i = blockIdx.x * blockDim.x + threadIdx.x;
    if (i >= E_TOT) return;
    int s, o, r;
    edge_decode(i, src, dst, rel, s, o, r);
    int2 cr = cnt2[r * N_NODES + s];
    float v = 1.0f / (float)cr.x;
    recs[off[s] + cr.y + rank[i]] = make_int2((r << 16) | o, __float_as_int(v));
}

// ---- K4: w1[r,n,e] = sum_b comps1[r,b] * bases1[b,n,e]  -> bf16 -------------
// r-tiled passes (RT<=14): float4 acc[RT] stays register-resident (~70 VGPR),
// bases1 streamed float4 once per pass; 3 passes total, passes 2-3 L3-hit.
template<int RT>
__device__ __forceinline__ void w1_pass(const float* __restrict__ comps1,
                                        const float4* __restrict__ b4,
                                        uint2* __restrict__ w1p2, int j4, int r0) {
    float4 acc[RT];
#pragma unroll
    for (int r = 0; r < RT; r++) { acc[r].x = 0.f; acc[r].y = 0.f; acc[r].z = 0.f; acc[r].w = 0.f; }
    for (int b = 0; b < NB; b++) {
        float4 bb = b4[(size_t)b * (NE_COL / 4) + j4];
#pragma unroll
        for (int r = 0; r < RT; r++) {
            float cc = comps1[(r0 + r) * NB + b];
            acc[r].x = fmaf(cc, bb.x, acc[r].x);
            acc[r].y = fmaf(cc, bb.y, acc[r].y);
            acc[r].z = fmaf(cc, bb.z, acc[r].z);
            acc[r].w = fmaf(cc, bb.w, acc[r].w);
        }
    }
#pragma unroll
    for (int r = 0; r < RT; r++) {
        uint2 pk;
        pk.x = ((unsigned)f2bf(acc[r].y) << 16) | (unsigned)f2bf(acc[r].x);
        pk.y = ((unsigned)f2bf(acc[r].w) << 16) | (unsigned)f2bf(acc[r].z);
        w1p2[(size_t)(r0 + r) * (NE_COL / 4) + j4] = pk;
    }
}

__global__ void __launch_bounds__(256, 2)
k_w1(const float* __restrict__ comps1, const float* __restrict__ bases1,
     uint2* __restrict__ w1p2) {
    int j4 = blockIdx.x * blockDim.x + threadIdx.x;
    if (j4 >= NE_COL / 4) return;
    const float4* b4 = (const float4*)bases1;
    w1_pass<14>(comps1, b4, w1p2, j4, 0);
    w1_pass<14>(comps1, b4, w1p2, j4, 14);
    w1_pass<13>(comps1, b4, w1p2, j4, 28);
}

// ---- K5: w2t[r,c,e] = sum_b comps2[r,b] * bases2[b,e,c]  (transposed) -------
__global__ void k_w2(const float* __restrict__ comps2, const float* __restrict__ bases2,
                     float* __restrict__ w2t) {
    int r = blockIdx.x;        // 41 blocks
    int t = threadIdx.x;       // 256 = NCLS*EMB, t = c*16+e
    int c = t >> 4, e = t & 15;
    float acc = 0.f;
#pragma unroll 8
    for (int b = 0; b < NB; b++) acc += comps2[r * NB + b] * bases2[b * (EMB * NCLS) + e * NCLS + c];
    w2t[r * (EMB * NCLS) + t] = acc;
}

// ---- K6: layer-1 gather, 8 lanes/edge: each lane loads one bf16x2 (uint) ----
// and produces h[s, 2*e2] and h[s, 2*e2+1]. Same per-element math order.
__global__ void k_l1_gather(const int* __restrict__ off, const int2* __restrict__ recs,
                            const unsigned* __restrict__ w1p,
                            const float* __restrict__ bias1, float* __restrict__ h) {
    int t = blockIdx.x * blockDim.x + threadIdx.x;     // N_NODES*8
    if (t >= N_NODES * 8) return;
    int s = t >> 3, e2 = t & 7;
    int beg = off[s], end = off[s + 1];
    float ax = 0.f, ay = 0.f;
    int j = beg;
    for (; j + 3 < end; j += 4) {
        int2 r0 = recs[j], r1 = recs[j + 1], r2 = recs[j + 2], r3 = recs[j + 3];
        unsigned p0 = w1p[(size_t)(r0.x >> 16) * (NE_COL / 2) + (r0.x & 0xFFFF) * 8 + e2];
        unsigned p1 = w1p[(size_t)(r1.x >> 16) * (NE_COL / 2) + (r1.x & 0xFFFF) * 8 + e2];
        unsigned p2 = w1p[(size_t)(r2.x >> 16) * (NE_COL / 2) + (r2.x & 0xFFFF) * 8 + e2];
        unsigned p3 = w1p[(size_t)(r3.x >> 16) * (NE_COL / 2) + (r3.x & 0xFFFF) * 8 + e2];
        float v0 = __int_as_float(r0.y), v1 = __int_as_float(r1.y);
        float v2 = __int_as_float(r2.y), v3 = __int_as_float(r3.y);
        ax = fmaf(v0, __uint_as_float(p0 << 16), ax);
        ay = fmaf(v0, __uint_as_float(p0 & 0xFFFF0000u), ay);
        ax = fmaf(v1, __uint_as_float(p1 << 16), ax);
        ay = fmaf(v1, __uint_as_float(p1 & 0xFFFF0000u), ay);
        ax = fmaf(v2, __uint_as_float(p2 << 16), ax);
        ay = fmaf(v2, __uint_as_float(p2 & 0xFFFF0000u), ay);
        ax = fmaf(v3, __uint_as_float(p3 << 16), ax);
        ay = fmaf(v3, __uint_as_float(p3 & 0xFFFF0000u), ay);
    }
    for (; j < end; j++) {
        int2 rc = recs[j];
        unsigned p = w1p[(size_t)(rc.x >> 16) * (NE_COL / 2) + (rc.x & 0xFFFF) * 8 + e2];
        float v = __int_as_float(rc.y);
        ax = fmaf(v, __uint_as_float(p << 16), ax);
        ay = fmaf(v, __uint_as_float(p & 0xFFFF0000u), ay);
    }
    float2 res;
    res.x = fmaxf(ax + bias1[2 * e2], 0.f);
    res.y = fmaxf(ay + bias1[2 * e2 + 1], 0.f);
    ((float2*)h)[t] = res;
}

// ---- K6-alt (fallback if ws too small for w1): on-the-fly basis contraction -
__global__ void k_l1_gather_fly(const int* __restrict__ off, const int2* __restrict__ recs,
                                const float* __restrict__ comps1,
                                const float* __restrict__ bases1,
                                const float* __restrict__ bias1, float* __restrict__ h) {
    __shared__ float c1[R_TOT * NB];
    for (int q = threadIdx.x; q < R_TOT * NB; q += blockDim.x) c1[q] = comps1[q];
    __syncthreads();
    int t = blockIdx.x * blockDim.x + threadIdx.x;
    int s = t >> 4, e = t & 15;
    int beg = off[s], end = off[s + 1];
    float acc = 0.f;
    for (int j = beg; j < end; j++) {
        int2 rec = recs[j];
        int o = rec.x & 0xFFFF, r = rec.x >> 16;
        float v = __int_as_float(rec.y);
        const float* cr = &c1[r * NB];
        float w = 0.f;
#pragma unroll 8
        for (int b = 0; b < NB; b++) w += cr[b] * bases1[(size_t)b * NE_COL + o * EMB + e];
        acc += v * w;
    }
    h[t] = fmaxf(acc + bias1[e], 0.f);
}

// ---- K7: layer-2 gather, no shfl: all 16 lanes of an edge-group load the ----
// same 64B h[o,:] row (L1 broadcast) and dot it with their w2 column from LDS.
#define W2C 20
#define W2R (16 * W2C + 4)    // 324
__global__ void k_l2_gather(const int* __restrict__ off, const int2* __restrict__ recs,
                            const float* __restrict__ h, const float* __restrict__ w2t,
                            const float* __restrict__ bias2, float* __restrict__ out) {
    __shared__ __align__(16) float w2s[R_TOT * W2R];   // 53,136 B -> 3 blocks/CU @512
    for (int q = threadIdx.x; q < R_TOT * (EMB * NCLS); q += blockDim.x) {
        int r = q >> 8;
        int x = q & 255;
        int c = x >> 4, e = x & 15;
        w2s[r * W2R + c * W2C + e] = w2t[q];
    }
    __syncthreads();
    int t = blockIdx.x * blockDim.x + threadIdx.x;
    if (t >= NE_COL) return;
    int s = t >> 4, c = t & 15;
    int beg = off[s], end = off[s + 1];
    int cbase = c * W2C;
    float acc = 0.f;
    int j = beg;
    for (; j + 1 < end; j += 2) {
        int2 ra = recs[j], rb = recs[j + 1];
        const float4* ha = (const float4*)(h + (size_t)(ra.x & 0xFFFF) * EMB);
        const float4* hb = (const float4*)(h + (size_t)(rb.x & 0xFFFF) * EMB);
        float4 h0 = ha[0], h1 = ha[1], h2 = ha[2], h3 = ha[3];
        float4 g0 = hb[0], g1 = hb[1], g2 = hb[2], g3 = hb[3];
        const float4* wa = (const float4*)&w2s[(ra.x >> 16) * W2R + cbase];
        const float4* wb = (const float4*)&w2s[(rb.x >> 16) * W2R + cbase];
        float4 a0 = wa[0], a1 = wa[1], a2 = wa[2], a3 = wa[3];
        float4 b0 = wb[0], b1 = wb[1], b2 = wb[2], b3 = wb[3];
        float da, db;
        da  = h0.x * a0.x; da = fmaf(h0.y, a0.y, da); da = fmaf(h0.z, a0.z, da); da = fmaf(h0.w, a0.w, da);
        da = fmaf(h1.x, a1.x, da); da = fmaf(h1.y, a1.y, da); da = fmaf(h1.z, a1.z, da); da = fmaf(h1.w, a1.w, da);
        da = fmaf(h2.x, a2.x, da); da = fmaf(h2.y, a2.y, da); da = fmaf(h2.z, a2.z, da); da = fmaf(h2.w, a2.w, da);
        da = fmaf(h3.x, a3.x, da); da = fmaf(h3.y, a3.y, da); da = fmaf(h3.z, a3.z, da); da = fmaf(h3.w, a3.w, da);
        db  = g0.x * b0.x; db = fmaf(g0.y, b0.y, db); db = fmaf(g0.z, b0.z, db); db = fmaf(g0.w, b0.w, db);
        db = fmaf(g1.x, b1.x, db); db = fmaf(g1.y, b1.y, db); db = fmaf(g1.z, b1.z, db); db = fmaf(g1.w, b1.w, db);
        db = fmaf(g2.x, b2.x, db); db = fmaf(g2.y, b2.y, db); db = fmaf(g2.z, b2.z, db); db = fmaf(g2.w, b2.w, db);
        db = fmaf(g3.x, b3.x, db); db = fmaf(g3.y, b3.y, db); db = fmaf(g3.z, b3.z, db); db = fmaf(g3.w, b3.w, db);
        acc = fmaf(__int_as_float(ra.y), da, acc);
        acc = fmaf(__int_as_float(rb.y), db, acc);
    }
    for (; j < end; j++) {
        int2 ra = recs[j];
        const float4* ha = (const float4*)(h + (size_t)(ra.x & 0xFFFF) * EMB);
        float4 h0 = ha[0], h1 = ha[1], h2 = ha[2], h3 = ha[3];
        const float4* wa = (const float4*)&w2s[(ra.x >> 16) * W2R + cbase];
        float4 a0 = wa[0], a1 = wa[1], a2 = wa[2], a3 = wa[3];
        float da;
        da  = h0.x * a0.x; da = fmaf(h0.y, a0.y, da); da = fmaf(h0.z, a0.z, da); da = fmaf(h0.w, a0.w, da);
        da = fmaf(h1.x, a1.x, da); da = fmaf(h1.y, a1.y, da); da = fmaf(h1.z, a1.z, da); da = fmaf(h1.w, a1.w, da);
        da = fmaf(h2.x, a2.x, da); da = fmaf(h2.y, a2.y, da); da = fmaf(h2.z, a2.z, da); da = fmaf(h2.w, a2.w, da);
        da = fmaf(h3.x, a3.x, da); da = fmaf(h3.y, a3.y, da); da = fmaf(h3.z, a3.z, da); da = fmaf(h3.w, a3.w, da);
        acc = fmaf(__int_as_float(ra.y), da, acc);
    }
    out[s * NCLS + c] = acc + bias2[c];
}

static inline size_t align64(size_t x) { return (x + 63) & ~(size_t)63; }

extern "C" void kernel_launch(void* const* d_in, const int* in_sizes, int n_in,
                              void* d_out, int out_size, void* d_ws, size_t ws_size,
                              hipStream_t stream) {
    const int*   src    = (const int*)d_in[0];
    const int*   dst    = (const int*)d_in[1];
    const int*   rel    = (const int*)d_in[2];
    const float* comps1 = (const float*)d_in[3];
    const float* bases1 = (const float*)d_in[4];
    const float* comps2 = (const float*)d_in[5];
    const float* bases2 = (const float*)d_in[6];
    const float* bias1  = (const float*)d_in[7];
    const float* bias2  = (const float*)d_in[8];
    float* out = (float*)d_out;
    (void)in_sizes; (void)n_in; (void)out_size;

    char* ws = (char*)d_ws;
    size_t off_b = 0;
    // w1 (bf16, 65.6 MB) first; cnt2 (16.4MB) + rank (4.2MB) alias its head
    // (both dead before k_w1 writes w1).
    unsigned short* w1 = (unsigned short*)ws;
    int2*  cnt2 = (int2*)ws;
    int*   rank = (int*)(ws + align64((size_t)R_TOT * N_NODES * 8));
    off_b = align64((size_t)R_TOT * NE_COL * 2);              // 65.6 MB
    int*   deg  = (int*)(ws + off_b);  off_b = align64(off_b + (size_t)N_NODES * 4);
    int*   off  = (int*)(ws + off_b);  off_b = align64(off_b + (size_t)(N_NODES + 1) * 4);
    int*   bsum = (int*)(ws + off_b);  off_b = align64(off_b + (size_t)256 * 4);
    int2*  recs = (int2*)(ws + off_b); off_b = align64(off_b + (size_t)E_TOT * 8);
    float* h    = (float*)(ws + off_b); off_b = align64(off_b + (size_t)NE_COL * 4);
    float* w2t  = (float*)(ws + off_b); off_b = align64(off_b + (size_t)R_TOT * EMB * NCLS * 4);
    const bool materialize_w1 = (ws_size >= off_b);
    if (!materialize_w1) {
        off_b = 0;
        cnt2 = (int2*)(ws + off_b);  off_b = align64(off_b + (size_t)R_TOT * N_NODES * 8);
        rank = (int*)(ws + off_b);   off_b = align64(off_b + (size_t)E_TOT * 4);
        deg  = (int*)(ws + off_b);   off_b = align64(off_b + (size_t)N_NODES * 4);
        off  = (int*)(ws + off_b);   off_b = align64(off_b + (size_t)(N_NODES + 1) * 4);
        bsum = (int*)(ws + off_b);   off_b = align64(off_b + (size_t)256 * 4);
        recs = (int2*)(ws + off_b);  off_b = align64(off_b + (size_t)E_TOT * 8);
        h    = (float*)(ws + off_b); off_b = align64(off_b + (size_t)NE_COL * 4);
        w2t  = (float*)(ws + off_b); off_b = align64(off_b + (size_t)R_TOT * EMB * NCLS * 4);
    }

    // zero counts (.x of cnt2; .y overwritten by k_degA)
    hipMemsetAsync(cnt2, 0, (size_t)R_TOT * N_NODES * 8, stream);

    const int BLK = 256;
    const int g_edge = (E_TOT + BLK - 1) / BLK;           // 4102
    const int g_w1   = (NE_COL / 4 + BLK - 1) / BLK;      // 782
    const int g_l1   = (N_NODES * 8 + BLK - 1) / BLK;     // 1563
    const int g_l1f  = (N_NODES * 16) / BLK;              // 3125 (fallback, 16-lane)
    const int g_l2   = (NE_COL + 511) / 512;              // 1563

    k_count<<<g_edge, BLK, 0, stream>>>(src, dst, rel, cnt2, rank);
    k_degA<<<NBLK_N, 256, 0, stream>>>(cnt2, deg, bsum);
    k_degB<<<1, 256, 0, stream>>>(bsum);
    k_degC<<<NBLK_N, 256, 0, stream>>>(deg, bsum, off);
    k_fill<<<g_edge, BLK, 0, stream>>>(src, dst, rel, cnt2, rank, off, recs);
    k_w2<<<R_TOT, EMB * NCLS, 0, stream>>>(comps2, bases2, w2t);

    if (materialize_w1) {
        k_w1<<<g_w1, BLK, 0, stream>>>(comps1, bases1, (uint2*)w1);  // overwrites cnt2/rank (dead)
        k_l1_gather<<<g_l1, BLK, 0, stream>>>(off, recs, (const unsigned*)w1, bias1, h);
    } else {
        k_l1_gather_fly<<<g_l1f, BLK, 0, stream>>>(off, recs, comps1, bases1, bias1, h);
    }

    k_l2_gather<<<g_l2, 512, 0, stream>>>(off, recs, h, w2t, bias2, out);
}